// Round 1
// baseline (719.075 us; speedup 1.0000x reference)
//
#include <hip/hip_runtime.h>

#define D 128
#define NC 40

// ---------------- graph build ----------------

// Detect whether edge_index was pushed as int64 (high dwords of first 256
// entries all zero => int64) or int32. Values are node ids < 50000, so the
// test is unambiguous for real data.
__global__ void detect_kernel(const int* __restrict__ ei, int* __restrict__ flag) {
    __shared__ int any;
    if (threadIdx.x == 0) any = 0;
    __syncthreads();
    if (ei[threadIdx.x * 2 + 1] != 0) any = 1;   // benign race
    __syncthreads();
    if (threadIdx.x == 0) *flag = (any == 0) ? 1 : 0;  // 1 == int64
}

__device__ __forceinline__ int load_idx(const int* ei, long long pos, int is64) {
    return is64 ? ei[pos * 2] : ei[pos];
}

__global__ void count_deg_kernel(const int* __restrict__ ei, const int* __restrict__ flag,
                                 int* __restrict__ deg, int E) {
    int e = blockIdx.x * blockDim.x + threadIdx.x;
    if (e >= E) return;
    int is64 = *flag;
    int d = load_idx(ei, (long long)E + e, is64);   // dst row
    atomicAdd(&deg[d], 1);
}

// single-block exclusive scan of deg -> rowptr (and fill cursor copy), plus dinv
__global__ void scan_kernel(const int* __restrict__ deg, int* __restrict__ rowptr,
                            int* __restrict__ fill, float* __restrict__ dinv, int n) {
    __shared__ int wsum[16];
    int t = threadIdx.x;            // 0..1023
    int lane = t & 63, w = t >> 6;  // 16 waves
    int base = 0;
    int nchunk = (n + 1023) >> 10;
    for (int c = 0; c < nchunk; ++c) {
        int i = (c << 10) + t;
        int v = (i < n) ? deg[i] : 0;
        int s = v;
        #pragma unroll
        for (int off = 1; off < 64; off <<= 1) {
            int x = __shfl_up(s, off, 64);
            if (lane >= off) s += x;
        }
        if (lane == 63) wsum[w] = s;
        __syncthreads();
        int wbase = 0, total = 0;
        #pragma unroll
        for (int j = 0; j < 16; ++j) {
            int ws_j = wsum[j];
            if (j < w) wbase += ws_j;
            total += ws_j;
        }
        int excl = wbase + s - v;
        if (i < n) {
            rowptr[i] = base + excl;
            fill[i]   = base + excl;
            dinv[i]   = rsqrtf((float)(v + 1));   // +1 self loop
        }
        __syncthreads();   // protect wsum before next chunk
        base += total;
    }
    if (t == 0) rowptr[n] = base;
}

__global__ void scatter_kernel(const int* __restrict__ ei, const int* __restrict__ flag,
                               int* __restrict__ fill, int* __restrict__ col, int E) {
    int e = blockIdx.x * blockDim.x + threadIdx.x;
    if (e >= E) return;
    int is64 = *flag;
    int s = load_idx(ei, (long long)e, is64);
    int d = load_idx(ei, (long long)E + e, is64);
    int pos = atomicAdd(&fill[d], 1);
    col[pos] = s;
}

// ---------------- dense GEMM  C[M x 128] = A[M x 128] @ W[128 x 128] ----------------
__launch_bounds__(256, 2)
__global__ void gemm128_kernel(const float* __restrict__ A, const float* __restrict__ W,
                               float* __restrict__ C, int M) {
    __shared__ float Ws[128 * 128];   // 64KB, [k][n]
    __shared__ float As[32][128];     // 16KB, [k][r] (transposed chunk)
    int t = threadIdx.x;
    {
        const float4* W4 = (const float4*)W;
        float4* Ws4 = (float4*)Ws;
        #pragma unroll
        for (int i = 0; i < 16; ++i) Ws4[i * 256 + t] = W4[i * 256 + t];
    }
    int row0 = blockIdx.x * 128;
    int ty = t >> 4, tx = t & 15;
    int r0 = ty * 8, c0 = tx * 8;
    float acc[8][8] = {};
    for (int kc = 0; kc < 128; kc += 32) {
        __syncthreads();
        #pragma unroll
        for (int q = 0; q < 4; ++q) {
            int f = q * 256 + t;
            int r = f >> 3;
            int k0 = (f & 7) * 4;
            int gr = row0 + r; if (gr >= M) gr = M - 1;
            float4 av = *(const float4*)&A[(size_t)gr * 128 + kc + k0];
            As[k0 + 0][r] = av.x;
            As[k0 + 1][r] = av.y;
            As[k0 + 2][r] = av.z;
            As[k0 + 3][r] = av.w;
        }
        __syncthreads();
        #pragma unroll
        for (int k = 0; k < 32; ++k) {
            float4 a0 = *(const float4*)&As[k][r0];
            float4 a1 = *(const float4*)&As[k][r0 + 4];
            float4 w0 = *(const float4*)&Ws[(kc + k) * 128 + c0];
            float4 w1 = *(const float4*)&Ws[(kc + k) * 128 + c0 + 4];
            float a[8] = {a0.x, a0.y, a0.z, a0.w, a1.x, a1.y, a1.z, a1.w};
            float wv[8] = {w0.x, w0.y, w0.z, w0.w, w1.x, w1.y, w1.z, w1.w};
            #pragma unroll
            for (int i = 0; i < 8; ++i)
                #pragma unroll
                for (int j = 0; j < 8; ++j)
                    acc[i][j] += a[i] * wv[j];
        }
    }
    #pragma unroll
    for (int i = 0; i < 8; ++i) {
        int gr = row0 + r0 + i;
        if (gr < M) {
            float4 o0 = {acc[i][0], acc[i][1], acc[i][2], acc[i][3]};
            float4 o1 = {acc[i][4], acc[i][5], acc[i][6], acc[i][7]};
            *(float4*)&C[(size_t)gr * 128 + c0]     = o0;
            *(float4*)&C[(size_t)gr * 128 + c0 + 4] = o1;
        }
    }
}

// ---------------- CSR aggregate + bias + relu ----------------
// out[n][t] = relu( dinv[n] * ( h[n][t]*dinv[n] + sum_{s in nbr(n)} h[s][t]*dinv[s] ) + b[t] )
__global__ void aggregate_kernel(const float* __restrict__ h, const float* __restrict__ dinv,
                                 const int* __restrict__ rowptr, const int* __restrict__ col,
                                 const float* __restrict__ bias, float* __restrict__ out, int n) {
    int node = blockIdx.x * blockDim.y + threadIdx.y;
    if (node >= n) return;
    int t = threadIdx.x;
    float dn = dinv[node];
    float acc = h[(size_t)node * 128 + t] * dn;       // self loop (x dn later)
    int e0 = rowptr[node], e1 = rowptr[node + 1];
    for (int e = e0; e < e1; ++e) {
        int s = col[e];
        acc += h[(size_t)s * 128 + t] * dinv[s];
    }
    out[(size_t)node * 128 + t] = fmaxf(acc * dn + bias[t], 0.f);
}

// ---------------- final GEMM  C[M x 40] = A[M x 128] @ Wf[128 x 40] + bf ----------------
__launch_bounds__(256)
__global__ void final_kernel(const float* __restrict__ A, const float* __restrict__ Wf,
                             const float* __restrict__ bf, float* __restrict__ C, int M) {
    __shared__ float Ws[128 * 40];    // 20KB
    __shared__ float As[64][129];     // ~33KB
    int t = threadIdx.x;
    for (int i = t; i < 128 * 40; i += 256) Ws[i] = Wf[i];
    int row0 = blockIdx.x * 64;
    #pragma unroll
    for (int q = 0; q < 8; ++q) {
        int f = q * 256 + t;
        int r = f >> 5;            // 0..63
        int k0 = (f & 31) * 4;
        int gr = row0 + r; if (gr >= M) gr = M - 1;
        float4 av = *(const float4*)&A[(size_t)gr * 128 + k0];
        As[r][k0] = av.x; As[r][k0 + 1] = av.y; As[r][k0 + 2] = av.z; As[r][k0 + 3] = av.w;
    }
    __syncthreads();
    int tx = t & 7, ty = t >> 3;      // tx: 8 col groups of 5, ty: 32 row threads x 2 rows
    int c0 = tx * 5;
    float acc0[5] = {}, acc1[5] = {};
    #pragma unroll 4
    for (int k = 0; k < 128; ++k) {
        float a0 = As[ty][k], a1 = As[ty + 32][k];
        #pragma unroll
        for (int j = 0; j < 5; ++j) {
            float w = Ws[k * 40 + c0 + j];
            acc0[j] += a0 * w;
            acc1[j] += a1 * w;
        }
    }
    int rr0 = row0 + ty, rr1 = row0 + ty + 32;
    #pragma unroll
    for (int j = 0; j < 5; ++j) {
        float b = bf[c0 + j];
        if (rr0 < M) C[(size_t)rr0 * 40 + c0 + j] = acc0[j] + b;
        if (rr1 < M) C[(size_t)rr1 * 40 + c0 + j] = acc1[j] + b;
    }
}

extern "C" void kernel_launch(void* const* d_in, const int* in_sizes, int n_in,
                              void* d_out, int out_size, void* d_ws, size_t ws_size,
                              hipStream_t stream) {
    const float* x  = (const float*)d_in[0];
    const int*   ei = (const int*)d_in[1];
    const float* W1 = (const float*)d_in[2];
    const float* b1 = (const float*)d_in[3];
    const float* Wh = (const float*)d_in[4];
    const float* bh = (const float*)d_in[5];
    const float* Wf = (const float*)d_in[6];
    const float* bf = (const float*)d_in[7];
    float* out = (float*)d_out;

    int n = in_sizes[0] / D;    // 50000
    int E = in_sizes[1] / 2;    // 800000

    char* ws = (char*)d_ws;
    size_t off = 0;
    auto alloc = [&](size_t bytes) {
        void* p = ws + off;
        off = (off + bytes + 255) & ~(size_t)255;
        return p;
    };
    float* B0     = (float*)alloc((size_t)n * D * 4);
    float* B1     = (float*)alloc((size_t)n * D * 4);
    int*   deg    = (int*)alloc((size_t)n * 4);
    int*   rowptr = (int*)alloc((size_t)(n + 1) * 4);
    int*   fill   = (int*)alloc((size_t)n * 4);
    int*   col    = (int*)alloc((size_t)E * 4);
    float* dinv   = (float*)alloc((size_t)n * 4);
    int*   flag   = (int*)alloc(256);

    hipMemsetAsync(deg, 0, (size_t)n * 4, stream);
    detect_kernel<<<1, 256, 0, stream>>>(ei, flag);
    count_deg_kernel<<<(E + 255) / 256, 256, 0, stream>>>(ei, flag, deg, E);
    scan_kernel<<<1, 1024, 0, stream>>>(deg, rowptr, fill, dinv, n);
    scatter_kernel<<<(E + 255) / 256, 256, 0, stream>>>(ei, flag, fill, col, E);

    int gblocks = (n + 127) / 128;
    dim3 ab(128, 2);
    int agrid = (n + 1) / 2;

    gemm128_kernel<<<gblocks, 256, 0, stream>>>(x, W1, B0, n);
    aggregate_kernel<<<agrid, ab, 0, stream>>>(B0, dinv, rowptr, col, b1, B1, n);
    gemm128_kernel<<<gblocks, 256, 0, stream>>>(B1, Wh, B0, n);
    aggregate_kernel<<<agrid, ab, 0, stream>>>(B0, dinv, rowptr, col, bh, B1, n);
    gemm128_kernel<<<gblocks, 256, 0, stream>>>(B1, Wh + D * D, B0, n);
    aggregate_kernel<<<agrid, ab, 0, stream>>>(B0, dinv, rowptr, col, bh + D, B1, n);
    final_kernel<<<(n + 63) / 64, 256, 0, stream>>>(B1, Wf, bf, out, n);
}

// Round 2
// 455.019 us; speedup vs baseline: 1.5803x; 1.5803x over previous
//
#include <hip/hip_runtime.h>

#define D 128
#define NC 40

// ---------------- graph build ----------------

__global__ void detect_kernel(const int* __restrict__ ei, int* __restrict__ flag) {
    __shared__ int any;
    if (threadIdx.x == 0) any = 0;
    __syncthreads();
    if (ei[threadIdx.x * 2 + 1] != 0) any = 1;   // benign race
    __syncthreads();
    if (threadIdx.x == 0) *flag = (any == 0) ? 1 : 0;  // 1 == int64
}

__device__ __forceinline__ int load_idx(const int* ei, long long pos, int is64) {
    return is64 ? ei[pos * 2] : ei[pos];
}

__global__ void count_deg_kernel(const int* __restrict__ ei, const int* __restrict__ flag,
                                 int* __restrict__ deg, int E) {
    int e = blockIdx.x * blockDim.x + threadIdx.x;
    if (e >= E) return;
    int is64 = *flag;
    int d = load_idx(ei, (long long)E + e, is64);   // dst row
    atomicAdd(&deg[d], 1);
}

// single-block exclusive scan of deg -> rowptr (+fill cursor), plus dinv
__global__ void scan_kernel(const int* __restrict__ deg, int* __restrict__ rowptr,
                            int* __restrict__ fill, float* __restrict__ dinv, int n) {
    __shared__ int wsum[16];
    int t = threadIdx.x;            // 0..1023
    int lane = t & 63, w = t >> 6;  // 16 waves
    int base = 0;
    int nchunk = (n + 1023) >> 10;
    for (int c = 0; c < nchunk; ++c) {
        int i = (c << 10) + t;
        int v = (i < n) ? deg[i] : 0;
        int s = v;
        #pragma unroll
        for (int off = 1; off < 64; off <<= 1) {
            int x = __shfl_up(s, off, 64);
            if (lane >= off) s += x;
        }
        if (lane == 63) wsum[w] = s;
        __syncthreads();
        int wbase = 0, total = 0;
        #pragma unroll
        for (int j = 0; j < 16; ++j) {
            int ws_j = wsum[j];
            if (j < w) wbase += ws_j;
            total += ws_j;
        }
        int excl = wbase + s - v;
        if (i < n) {
            rowptr[i] = base + excl;
            fill[i]   = base + excl;
            dinv[i]   = rsqrtf((float)(v + 1));   // +1 self loop
        }
        __syncthreads();   // protect wsum before next chunk
        base += total;
    }
    if (t == 0) rowptr[n] = base;
}

// scatter edge -> CSR, packing {src, dinv[src]} as int2 (kills a dependent
// random gather in the aggregate hot loop)
__global__ void scatter_kernel(const int* __restrict__ ei, const int* __restrict__ flag,
                               int* __restrict__ fill, const float* __restrict__ dinv,
                               int2* __restrict__ col2, int E) {
    int e = blockIdx.x * blockDim.x + threadIdx.x;
    if (e >= E) return;
    int is64 = *flag;
    int s = load_idx(ei, (long long)e, is64);
    int d = load_idx(ei, (long long)E + e, is64);
    int pos = atomicAdd(&fill[d], 1);
    col2[pos] = make_int2(s, __float_as_int(dinv[s]));
}

// ---------------- dense GEMM  C[M x 128] = A[M x 128] @ W[128 x 128] ----------------
// 64-row M-tiles: 782 blocks for load balance (vs 391 at 128-row tiles, which
// stragglers half the machine). LDS 72KB -> 2 blocks/CU.
__launch_bounds__(256, 2)
__global__ void gemm128_kernel(const float* __restrict__ A, const float* __restrict__ W,
                               float* __restrict__ C, int M) {
    __shared__ float Ws[128 * 128];   // 64KB, [k][n]
    __shared__ float As[32][64];      // 8KB, [k][r] (transposed chunk)
    int t = threadIdx.x;
    {
        const float4* W4 = (const float4*)W;
        float4* Ws4 = (float4*)Ws;
        #pragma unroll
        for (int i = 0; i < 16; ++i) Ws4[i * 256 + t] = W4[i * 256 + t];
    }
    int row0 = blockIdx.x * 64;
    int ty = t >> 4, tx = t & 15;
    int r0 = ty * 4, c0 = tx * 8;     // 4 rows x 8 cols per thread
    float acc[4][8] = {};
    for (int kc = 0; kc < 128; kc += 32) {
        __syncthreads();
        #pragma unroll
        for (int q = 0; q < 2; ++q) {
            int f = q * 256 + t;       // 0..511
            int r = f >> 3;            // 0..63
            int k0 = (f & 7) * 4;
            int gr = row0 + r; if (gr >= M) gr = M - 1;
            float4 av = *(const float4*)&A[(size_t)gr * 128 + kc + k0];
            As[k0 + 0][r] = av.x;
            As[k0 + 1][r] = av.y;
            As[k0 + 2][r] = av.z;
            As[k0 + 3][r] = av.w;
        }
        __syncthreads();
        #pragma unroll
        for (int k = 0; k < 32; ++k) {
            float4 a0 = *(const float4*)&As[k][r0];
            float4 w0 = *(const float4*)&Ws[(kc + k) * 128 + c0];
            float4 w1 = *(const float4*)&Ws[(kc + k) * 128 + c0 + 4];
            float a[4] = {a0.x, a0.y, a0.z, a0.w};
            float wv[8] = {w0.x, w0.y, w0.z, w0.w, w1.x, w1.y, w1.z, w1.w};
            #pragma unroll
            for (int i = 0; i < 4; ++i)
                #pragma unroll
                for (int j = 0; j < 8; ++j)
                    acc[i][j] += a[i] * wv[j];
        }
    }
    #pragma unroll
    for (int i = 0; i < 4; ++i) {
        int gr = row0 + r0 + i;
        if (gr < M) {
            float4 o0 = {acc[i][0], acc[i][1], acc[i][2], acc[i][3]};
            float4 o1 = {acc[i][4], acc[i][5], acc[i][6], acc[i][7]};
            *(float4*)&C[(size_t)gr * 128 + c0]     = o0;
            *(float4*)&C[(size_t)gr * 128 + c0 + 4] = o1;
        }
    }
}

// ---------------- CSR aggregate + bias + relu ----------------
// 32 lanes x float4 per node (one wave-load per gathered row), 8-deep
// software pipeline for memory-level parallelism.
__launch_bounds__(256)
__global__ void aggregate_kernel(const float4* __restrict__ h4, const float* __restrict__ dinv,
                                 const int* __restrict__ rowptr, const int2* __restrict__ col2,
                                 const float* __restrict__ bias, float4* __restrict__ out4, int n) {
    int node = blockIdx.x * 8 + (threadIdx.x >> 5);
    if (node >= n) return;
    int l = threadIdx.x & 31;
    float dn = dinv[node];
    size_t rowbase = (size_t)node * 32;
    float4 hv = h4[rowbase + l];
    float4 acc;
    acc.x = hv.x * dn; acc.y = hv.y * dn; acc.z = hv.z * dn; acc.w = hv.w * dn;
    int e = rowptr[node], e1 = rowptr[node + 1];
    for (; e + 8 <= e1; e += 8) {
        int2 c[8];
        #pragma unroll
        for (int j = 0; j < 8; ++j) c[j] = col2[e + j];
        float4 v[8];
        #pragma unroll
        for (int j = 0; j < 8; ++j) v[j] = h4[(size_t)c[j].x * 32 + l];
        #pragma unroll
        for (int j = 0; j < 8; ++j) {
            float ds = __int_as_float(c[j].y);
            acc.x += v[j].x * ds; acc.y += v[j].y * ds;
            acc.z += v[j].z * ds; acc.w += v[j].w * ds;
        }
    }
    for (; e + 4 <= e1; e += 4) {
        int2 c[4];
        #pragma unroll
        for (int j = 0; j < 4; ++j) c[j] = col2[e + j];
        float4 v[4];
        #pragma unroll
        for (int j = 0; j < 4; ++j) v[j] = h4[(size_t)c[j].x * 32 + l];
        #pragma unroll
        for (int j = 0; j < 4; ++j) {
            float ds = __int_as_float(c[j].y);
            acc.x += v[j].x * ds; acc.y += v[j].y * ds;
            acc.z += v[j].z * ds; acc.w += v[j].w * ds;
        }
    }
    for (; e < e1; ++e) {
        int2 c = col2[e];
        float ds = __int_as_float(c.y);
        float4 v = h4[(size_t)c.x * 32 + l];
        acc.x += v.x * ds; acc.y += v.y * ds; acc.z += v.z * ds; acc.w += v.w * ds;
    }
    float4 bv = *(const float4*)&bias[l * 4];
    float4 o;
    o.x = fmaxf(acc.x * dn + bv.x, 0.f);
    o.y = fmaxf(acc.y * dn + bv.y, 0.f);
    o.z = fmaxf(acc.z * dn + bv.z, 0.f);
    o.w = fmaxf(acc.w * dn + bv.w, 0.f);
    out4[rowbase + l] = o;
}

// ---------------- final GEMM  C[M x 40] = A[M x 128] @ Wf[128 x 40] + bf ----------------
__launch_bounds__(256)
__global__ void final_kernel(const float* __restrict__ A, const float* __restrict__ Wf,
                             const float* __restrict__ bf, float* __restrict__ C, int M) {
    __shared__ float Ws[128 * 40];    // 20KB
    __shared__ float As[64][129];     // ~33KB
    int t = threadIdx.x;
    for (int i = t; i < 128 * 40; i += 256) Ws[i] = Wf[i];
    int row0 = blockIdx.x * 64;
    #pragma unroll
    for (int q = 0; q < 8; ++q) {
        int f = q * 256 + t;
        int r = f >> 5;            // 0..63
        int k0 = (f & 31) * 4;
        int gr = row0 + r; if (gr >= M) gr = M - 1;
        float4 av = *(const float4*)&A[(size_t)gr * 128 + k0];
        As[r][k0] = av.x; As[r][k0 + 1] = av.y; As[r][k0 + 2] = av.z; As[r][k0 + 3] = av.w;
    }
    __syncthreads();
    int tx = t & 7, ty = t >> 3;
    int c0 = tx * 5;
    float acc0[5] = {}, acc1[5] = {};
    #pragma unroll 4
    for (int k = 0; k < 128; ++k) {
        float a0 = As[ty][k], a1 = As[ty + 32][k];
        #pragma unroll
        for (int j = 0; j < 5; ++j) {
            float w = Ws[k * 40 + c0 + j];
            acc0[j] += a0 * w;
            acc1[j] += a1 * w;
        }
    }
    int rr0 = row0 + ty, rr1 = row0 + ty + 32;
    #pragma unroll
    for (int j = 0; j < 5; ++j) {
        float b = bf[c0 + j];
        if (rr0 < M) C[(size_t)rr0 * 40 + c0 + j] = acc0[j] + b;
        if (rr1 < M) C[(size_t)rr1 * 40 + c0 + j] = acc1[j] + b;
    }
}

extern "C" void kernel_launch(void* const* d_in, const int* in_sizes, int n_in,
                              void* d_out, int out_size, void* d_ws, size_t ws_size,
                              hipStream_t stream) {
    const float* x  = (const float*)d_in[0];
    const int*   ei = (const int*)d_in[1];
    const float* W1 = (const float*)d_in[2];
    const float* b1 = (const float*)d_in[3];
    const float* Wh = (const float*)d_in[4];
    const float* bh = (const float*)d_in[5];
    const float* Wf = (const float*)d_in[6];
    const float* bf = (const float*)d_in[7];
    float* out = (float*)d_out;

    int n = in_sizes[0] / D;    // 50000
    int E = in_sizes[1] / 2;    // 800000

    char* ws = (char*)d_ws;
    size_t off = 0;
    auto alloc = [&](size_t bytes) {
        void* p = ws + off;
        off = (off + bytes + 255) & ~(size_t)255;
        return p;
    };
    float* B0     = (float*)alloc((size_t)n * D * 4);
    float* B1     = (float*)alloc((size_t)n * D * 4);
    int*   deg    = (int*)alloc((size_t)n * 4);
    int*   rowptr = (int*)alloc((size_t)(n + 1) * 4);
    int*   fill   = (int*)alloc((size_t)n * 4);
    int2*  col2   = (int2*)alloc((size_t)E * 8);
    float* dinv   = (float*)alloc((size_t)n * 4);
    int*   flag   = (int*)alloc(256);

    hipMemsetAsync(deg, 0, (size_t)n * 4, stream);
    detect_kernel<<<1, 256, 0, stream>>>(ei, flag);
    count_deg_kernel<<<(E + 255) / 256, 256, 0, stream>>>(ei, flag, deg, E);
    scan_kernel<<<1, 1024, 0, stream>>>(deg, rowptr, fill, dinv, n);
    scatter_kernel<<<(E + 255) / 256, 256, 0, stream>>>(ei, flag, fill, dinv, col2, E);

    int gblocks = (n + 63) / 64;
    int agrid = (n + 7) / 8;

    gemm128_kernel<<<gblocks, 256, 0, stream>>>(x, W1, B0, n);
    aggregate_kernel<<<agrid, 256, 0, stream>>>((const float4*)B0, dinv, rowptr, col2, b1, (float4*)B1, n);
    gemm128_kernel<<<gblocks, 256, 0, stream>>>(B1, Wh, B0, n);
    aggregate_kernel<<<agrid, 256, 0, stream>>>((const float4*)B0, dinv, rowptr, col2, bh, (float4*)B1, n);
    gemm128_kernel<<<gblocks, 256, 0, stream>>>(B1, Wh + D * D, B0, n);
    aggregate_kernel<<<agrid, 256, 0, stream>>>((const float4*)B0, dinv, rowptr, col2, bh + D, (float4*)B1, n);
    final_kernel<<<(n + 63) / 64, 256, 0, stream>>>(B1, Wf, bf, out, n);
}

// Round 3
// 379.774 us; speedup vs baseline: 1.8934x; 1.1981x over previous
//
#include <hip/hip_runtime.h>

#define D 128
#define NC 40

typedef __attribute__((ext_vector_type(8))) short short8v;
typedef __attribute__((ext_vector_type(4))) float f32x4;

__device__ __forceinline__ unsigned short f2bf(float f) {
    unsigned u = __float_as_uint(f);
    u += 0x7fff + ((u >> 16) & 1);          // RNE
    return (unsigned short)(u >> 16);
}
__device__ __forceinline__ float bf2f(unsigned short h) {
    return __uint_as_float(((unsigned)h) << 16);
}

// ---------------- graph build ----------------

__global__ void detect_kernel(const int* __restrict__ ei, int* __restrict__ flag) {
    __shared__ int any;
    if (threadIdx.x == 0) any = 0;
    __syncthreads();
    if (ei[threadIdx.x * 2 + 1] != 0) any = 1;   // benign race
    __syncthreads();
    if (threadIdx.x == 0) *flag = (any == 0) ? 1 : 0;  // 1 == int64
}

__device__ __forceinline__ int load_idx(const int* ei, long long pos, int is64) {
    return is64 ? ei[pos * 2] : ei[pos];
}

__global__ void count_deg_kernel(const int* __restrict__ ei, const int* __restrict__ flag,
                                 int* __restrict__ deg, int E) {
    int e = blockIdx.x * blockDim.x + threadIdx.x;
    if (e >= E) return;
    int is64 = *flag;
    int d = load_idx(ei, (long long)E + e, is64);   // dst row
    atomicAdd(&deg[d], 1);
}

// single-block exclusive scan of deg -> rowptr (+fill cursor), plus dinv
__global__ void scan_kernel(const int* __restrict__ deg, int* __restrict__ rowptr,
                            int* __restrict__ fill, float* __restrict__ dinv, int n) {
    __shared__ int wsum[16];
    int t = threadIdx.x;            // 0..1023
    int lane = t & 63, w = t >> 6;  // 16 waves
    int base = 0;
    int nchunk = (n + 1023) >> 10;
    for (int c = 0; c < nchunk; ++c) {
        int i = (c << 10) + t;
        int v = (i < n) ? deg[i] : 0;
        int s = v;
        #pragma unroll
        for (int off = 1; off < 64; off <<= 1) {
            int x = __shfl_up(s, off, 64);
            if (lane >= off) s += x;
        }
        if (lane == 63) wsum[w] = s;
        __syncthreads();
        int wbase = 0, total = 0;
        #pragma unroll
        for (int j = 0; j < 16; ++j) {
            int ws_j = wsum[j];
            if (j < w) wbase += ws_j;
            total += ws_j;
        }
        int excl = wbase + s - v;
        if (i < n) {
            rowptr[i] = base + excl;
            fill[i]   = base + excl;
            dinv[i]   = rsqrtf((float)(v + 1));   // +1 self loop
        }
        __syncthreads();   // protect wsum before next chunk
        base += total;
    }
    if (t == 0) rowptr[n] = base;
}

// scatter edge -> CSR, packing {src, dinv[src]}
__global__ void scatter_kernel(const int* __restrict__ ei, const int* __restrict__ flag,
                               int* __restrict__ fill, const float* __restrict__ dinv,
                               int2* __restrict__ col2, int E) {
    int e = blockIdx.x * blockDim.x + threadIdx.x;
    if (e >= E) return;
    int is64 = *flag;
    int s = load_idx(ei, (long long)e, is64);
    int d = load_idx(ei, (long long)E + e, is64);
    int pos = atomicAdd(&fill[d], 1);
    col2[pos] = make_int2(s, __float_as_int(dinv[s]));
}

// ---------------- split-bf16 MFMA GEMM  C[M x 128] = A[M x 128] @ W[128 x 128] ----
// f32 A split into hi/lo bf16 during LDS staging; W split into per-wave register
// fragments. C = Ahi*Whi + Ahi*Wlo + Alo*Whi (lo*lo dropped, ~2^-17 rel err).
// BM=64 -> 782 blocks. LDS 32KB (Ah+Al), XOR-swizzled (G4) for frag reads.
__launch_bounds__(256)
__global__ void gemm128_mfma_kernel(const float* __restrict__ A, const float* __restrict__ W,
                                    float* __restrict__ C, int M) {
    __shared__ unsigned short Ah[64 * 128];   // 16KB, swizzled row-major [row][k]
    __shared__ unsigned short Al[64 * 128];   // 16KB
    int t = threadIdx.x;
    int l = t & 63, w = t >> 6;
    int lr = l & 15, lh = l >> 4;

    // --- W fragments into registers: wave w owns cols n0..n0+31 ---
    short8v bhi[2][4], blo[2][4];
    int n0 = w * 32;
    #pragma unroll
    for (int ni = 0; ni < 2; ++ni) {
        #pragma unroll
        for (int ks = 0; ks < 4; ++ks) {
            int n = n0 + ni * 16 + lr;
            int kb = ks * 32 + lh * 8;
            #pragma unroll
            for (int j = 0; j < 8; ++j) {
                float wv = W[(kb + j) * 128 + n];
                unsigned short hi = f2bf(wv);
                unsigned short lo = f2bf(wv - bf2f(hi));
                bhi[ni][ks][j] = (short)hi;
                blo[ni][ks][j] = (short)lo;
            }
        }
    }

    // --- stage A tile (64 rows x 128 k), f32 -> hi/lo bf16, swizzled ---
    int row0 = blockIdx.x * 64;
    #pragma unroll
    for (int c = 0; c < 4; ++c) {
        int chunk = c * 256 + t;          // 0..1023
        int r  = chunk >> 4;              // 0..63
        int kc = chunk & 15;              // 16B chunk within row (8 bf16)
        int gr = row0 + r; if (gr >= M) gr = M - 1;
        float4 a0 = *(const float4*)&A[(size_t)gr * 128 + kc * 8];
        float4 a1 = *(const float4*)&A[(size_t)gr * 128 + kc * 8 + 4];
        float av[8] = {a0.x, a0.y, a0.z, a0.w, a1.x, a1.y, a1.z, a1.w};
        short8v hv, lv;
        #pragma unroll
        for (int j = 0; j < 8; ++j) {
            unsigned short hi = f2bf(av[j]);
            hv[j] = (short)hi;
            lv[j] = (short)f2bf(av[j] - bf2f(hi));
        }
        int off = (r << 8) + ((kc << 4) ^ ((r & 7) << 4));   // byte offset
        *(short8v*)((char*)Ah + off) = hv;
        *(short8v*)((char*)Al + off) = lv;
    }
    __syncthreads();

    // --- MFMA: wave computes 64 rows x 32 cols ---
    f32x4 acc[4][2];
    #pragma unroll
    for (int mi = 0; mi < 4; ++mi)
        #pragma unroll
        for (int ni = 0; ni < 2; ++ni)
            acc[mi][ni] = (f32x4){0.f, 0.f, 0.f, 0.f};

    #pragma unroll
    for (int mi = 0; mi < 4; ++mi) {
        int row = mi * 16 + lr;
        #pragma unroll
        for (int ks = 0; ks < 4; ++ks) {
            int off = (row << 8) + (((ks << 6) + (lh << 4)) ^ ((row & 7) << 4));
            short8v ah = *(short8v*)((char*)Ah + off);
            short8v al = *(short8v*)((char*)Al + off);
            #pragma unroll
            for (int ni = 0; ni < 2; ++ni) {
                acc[mi][ni] = __builtin_amdgcn_mfma_f32_16x16x32_bf16(ah, bhi[ni][ks], acc[mi][ni], 0, 0, 0);
                acc[mi][ni] = __builtin_amdgcn_mfma_f32_16x16x32_bf16(ah, blo[ni][ks], acc[mi][ni], 0, 0, 0);
                acc[mi][ni] = __builtin_amdgcn_mfma_f32_16x16x32_bf16(al, bhi[ni][ks], acc[mi][ni], 0, 0, 0);
            }
        }
    }

    // --- write C: D layout col=lane&15, row=(lane>>4)*4+reg ---
    #pragma unroll
    for (int mi = 0; mi < 4; ++mi) {
        #pragma unroll
        for (int ni = 0; ni < 2; ++ni) {
            #pragma unroll
            for (int r = 0; r < 4; ++r) {
                int row = row0 + mi * 16 + lh * 4 + r;
                if (row < M) C[(size_t)row * 128 + n0 + ni * 16 + lr] = acc[mi][ni][r];
            }
        }
    }
}

// ---------------- CSR aggregate + bias + relu ----------------
__launch_bounds__(256)
__global__ void aggregate_kernel(const float4* __restrict__ h4, const float* __restrict__ dinv,
                                 const int* __restrict__ rowptr, const int2* __restrict__ col2,
                                 const float* __restrict__ bias, float4* __restrict__ out4, int n) {
    int node = blockIdx.x * 8 + (threadIdx.x >> 5);
    if (node >= n) return;
    int l = threadIdx.x & 31;
    float dn = dinv[node];
    size_t rowbase = (size_t)node * 32;
    float4 hv = h4[rowbase + l];
    float4 acc;
    acc.x = hv.x * dn; acc.y = hv.y * dn; acc.z = hv.z * dn; acc.w = hv.w * dn;
    int e = rowptr[node], e1 = rowptr[node + 1];
    for (; e + 8 <= e1; e += 8) {
        int2 c[8];
        #pragma unroll
        for (int j = 0; j < 8; ++j) c[j] = col2[e + j];
        float4 v[8];
        #pragma unroll
        for (int j = 0; j < 8; ++j) v[j] = h4[(size_t)c[j].x * 32 + l];
        #pragma unroll
        for (int j = 0; j < 8; ++j) {
            float ds = __int_as_float(c[j].y);
            acc.x += v[j].x * ds; acc.y += v[j].y * ds;
            acc.z += v[j].z * ds; acc.w += v[j].w * ds;
        }
    }
    for (; e + 4 <= e1; e += 4) {
        int2 c[4];
        #pragma unroll
        for (int j = 0; j < 4; ++j) c[j] = col2[e + j];
        float4 v[4];
        #pragma unroll
        for (int j = 0; j < 4; ++j) v[j] = h4[(size_t)c[j].x * 32 + l];
        #pragma unroll
        for (int j = 0; j < 4; ++j) {
            float ds = __int_as_float(c[j].y);
            acc.x += v[j].x * ds; acc.y += v[j].y * ds;
            acc.z += v[j].z * ds; acc.w += v[j].w * ds;
        }
    }
    for (; e < e1; ++e) {
        int2 c = col2[e];
        float ds = __int_as_float(c.y);
        float4 v = h4[(size_t)c.x * 32 + l];
        acc.x += v.x * ds; acc.y += v.y * ds; acc.z += v.z * ds; acc.w += v.w * ds;
    }
    float4 bv = *(const float4*)&bias[l * 4];
    float4 o;
    o.x = fmaxf(acc.x * dn + bv.x, 0.f);
    o.y = fmaxf(acc.y * dn + bv.y, 0.f);
    o.z = fmaxf(acc.z * dn + bv.z, 0.f);
    o.w = fmaxf(acc.w * dn + bv.w, 0.f);
    out4[rowbase + l] = o;
}

// ---------------- final GEMM  C[M x 40] = A[M x 128] @ Wf[128 x 40] + bf ----------------
__launch_bounds__(256)
__global__ void final_kernel(const float* __restrict__ A, const float* __restrict__ Wf,
                             const float* __restrict__ bf, float* __restrict__ C, int M) {
    __shared__ float Ws[128 * 40];    // 20KB
    __shared__ float As[64][129];     // ~33KB
    int t = threadIdx.x;
    for (int i = t; i < 128 * 40; i += 256) Ws[i] = Wf[i];
    int row0 = blockIdx.x * 64;
    #pragma unroll
    for (int q = 0; q < 8; ++q) {
        int f = q * 256 + t;
        int r = f >> 5;            // 0..63
        int k0 = (f & 31) * 4;
        int gr = row0 + r; if (gr >= M) gr = M - 1;
        float4 av = *(const float4*)&A[(size_t)gr * 128 + k0];
        As[r][k0] = av.x; As[r][k0 + 1] = av.y; As[r][k0 + 2] = av.z; As[r][k0 + 3] = av.w;
    }
    __syncthreads();
    int tx = t & 7, ty = t >> 3;
    int c0 = tx * 5;
    float acc0[5] = {}, acc1[5] = {};
    #pragma unroll 4
    for (int k = 0; k < 128; ++k) {
        float a0 = As[ty][k], a1 = As[ty + 32][k];
        #pragma unroll
        for (int j = 0; j < 5; ++j) {
            float w = Ws[k * 40 + c0 + j];
            acc0[j] += a0 * w;
            acc1[j] += a1 * w;
        }
    }
    int rr0 = row0 + ty, rr1 = row0 + ty + 32;
    #pragma unroll
    for (int j = 0; j < 5; ++j) {
        float b = bf[c0 + j];
        if (rr0 < M) C[(size_t)rr0 * 40 + c0 + j] = acc0[j] + b;
        if (rr1 < M) C[(size_t)rr1 * 40 + c0 + j] = acc1[j] + b;
    }
}

extern "C" void kernel_launch(void* const* d_in, const int* in_sizes, int n_in,
                              void* d_out, int out_size, void* d_ws, size_t ws_size,
                              hipStream_t stream) {
    const float* x  = (const float*)d_in[0];
    const int*   ei = (const int*)d_in[1];
    const float* W1 = (const float*)d_in[2];
    const float* b1 = (const float*)d_in[3];
    const float* Wh = (const float*)d_in[4];
    const float* bh = (const float*)d_in[5];
    const float* Wf = (const float*)d_in[6];
    const float* bf = (const float*)d_in[7];
    float* out = (float*)d_out;

    int n = in_sizes[0] / D;    // 50000
    int E = in_sizes[1] / 2;    // 800000

    char* ws = (char*)d_ws;
    size_t off = 0;
    auto alloc = [&](size_t bytes) {
        void* p = ws + off;
        off = (off + bytes + 255) & ~(size_t)255;
        return p;
    };
    float* B0     = (float*)alloc((size_t)n * D * 4);
    float* B1     = (float*)alloc((size_t)n * D * 4);
    int*   deg    = (int*)alloc((size_t)n * 4);
    int*   rowptr = (int*)alloc((size_t)(n + 1) * 4);
    int*   fill   = (int*)alloc((size_t)n * 4);
    int2*  col2   = (int2*)alloc((size_t)E * 8);
    float* dinv   = (float*)alloc((size_t)n * 4);
    int*   flag   = (int*)alloc(256);

    hipMemsetAsync(deg, 0, (size_t)n * 4, stream);
    detect_kernel<<<1, 256, 0, stream>>>(ei, flag);
    count_deg_kernel<<<(E + 255) / 256, 256, 0, stream>>>(ei, flag, deg, E);
    scan_kernel<<<1, 1024, 0, stream>>>(deg, rowptr, fill, dinv, n);
    scatter_kernel<<<(E + 255) / 256, 256, 0, stream>>>(ei, flag, fill, dinv, col2, E);

    int gblocks = (n + 63) / 64;
    int agrid = (n + 7) / 8;

    gemm128_mfma_kernel<<<gblocks, 256, 0, stream>>>(x, W1, B0, n);
    aggregate_kernel<<<agrid, 256, 0, stream>>>((const float4*)B0, dinv, rowptr, col2, b1, (float4*)B1, n);
    gemm128_mfma_kernel<<<gblocks, 256, 0, stream>>>(B1, Wh, B0, n);
    aggregate_kernel<<<agrid, 256, 0, stream>>>((const float4*)B0, dinv, rowptr, col2, bh, (float4*)B1, n);
    gemm128_mfma_kernel<<<gblocks, 256, 0, stream>>>(B1, Wh + D * D, B0, n);
    aggregate_kernel<<<agrid, 256, 0, stream>>>((const float4*)B0, dinv, rowptr, col2, bh + D, (float4*)B1, n);
    final_kernel<<<(n + 63) / 64, 256, 0, stream>>>(B1, Wf, bf, out, n);
}

// Round 4
// 355.349 us; speedup vs baseline: 2.0236x; 1.0687x over previous
//
#include <hip/hip_runtime.h>

#define D 128
#define NC 40

typedef __attribute__((ext_vector_type(8))) short short8v;
typedef __attribute__((ext_vector_type(4))) float f32x4;

__device__ __forceinline__ unsigned short f2bf(float f) {
    unsigned u = __float_as_uint(f);
    u += 0x7fff + ((u >> 16) & 1);          // RNE
    return (unsigned short)(u >> 16);
}
__device__ __forceinline__ float bf2f(unsigned short h) {
    return __uint_as_float(((unsigned)h) << 16);
}

// ---------------- graph build ----------------

__global__ void detect_kernel(const int* __restrict__ ei, int* __restrict__ flag) {
    __shared__ int any;
    if (threadIdx.x == 0) any = 0;
    __syncthreads();
    if (ei[threadIdx.x * 2 + 1] != 0) any = 1;   // benign race
    __syncthreads();
    if (threadIdx.x == 0) *flag = (any == 0) ? 1 : 0;  // 1 == int64
}

__device__ __forceinline__ int load_idx(const int* ei, long long pos, int is64) {
    return is64 ? ei[pos * 2] : ei[pos];
}

__global__ void count_deg_kernel(const int* __restrict__ ei, const int* __restrict__ flag,
                                 int* __restrict__ deg, int E) {
    int e = blockIdx.x * blockDim.x + threadIdx.x;
    if (e >= E) return;
    int is64 = *flag;
    int d = load_idx(ei, (long long)E + e, is64);   // dst row
    atomicAdd(&deg[d], 1);
}

// 3-phase parallel exclusive scan (replaces 1-block serial scan: 1 CU can't
// stream 800KB quickly).
__global__ void scan1_kernel(const int* __restrict__ deg, int* __restrict__ bsum, int n) {
    int i = blockIdx.x * 256 + threadIdx.x;
    int v = (i < n) ? deg[i] : 0;
    #pragma unroll
    for (int off = 32; off; off >>= 1) v += __shfl_down(v, off, 64);
    __shared__ int ws[4];
    if ((threadIdx.x & 63) == 0) ws[threadIdx.x >> 6] = v;
    __syncthreads();
    if (threadIdx.x == 0) bsum[blockIdx.x] = ws[0] + ws[1] + ws[2] + ws[3];
}

__global__ void scan2_kernel(int* __restrict__ bsum, int* __restrict__ total, int nb) {
    int t = threadIdx.x;                 // 1024 threads, nb <= 1024
    int lane = t & 63, w = t >> 6;
    int v = (t < nb) ? bsum[t] : 0;
    int s = v;
    #pragma unroll
    for (int off = 1; off < 64; off <<= 1) {
        int x = __shfl_up(s, off, 64);
        if (lane >= off) s += x;
    }
    __shared__ int wsum[16];
    if (lane == 63) wsum[w] = s;
    __syncthreads();
    int wbase = 0;
    #pragma unroll
    for (int j = 0; j < 16; ++j) if (j < w) wbase += wsum[j];
    int excl = wbase + s - v;
    if (t < nb) bsum[t] = excl;
    if (t == nb - 1) *total = excl + v;
}

__global__ void scan3_kernel(const int* __restrict__ deg, const int* __restrict__ bsum,
                             const int* __restrict__ total, int* __restrict__ rowptr,
                             int* __restrict__ fill, float* __restrict__ dinv, int n) {
    int i = blockIdx.x * 256 + threadIdx.x;
    int v = (i < n) ? deg[i] : 0;
    int lane = threadIdx.x & 63, w = threadIdx.x >> 6;
    int s = v;
    #pragma unroll
    for (int off = 1; off < 64; off <<= 1) {
        int x = __shfl_up(s, off, 64);
        if (lane >= off) s += x;
    }
    __shared__ int wsum[4];
    if (lane == 63) wsum[w] = s;
    __syncthreads();
    int wbase = 0;
    #pragma unroll
    for (int j = 0; j < 4; ++j) if (j < w) wbase += wsum[j];
    int excl = bsum[blockIdx.x] + wbase + s - v;
    if (i < n) {
        rowptr[i] = excl;
        fill[i]   = excl;
        dinv[i]   = rsqrtf((float)(v + 1));   // +1 self loop
    }
    if (i == 0) rowptr[n] = *total;
}

// scatter edge -> CSR, packing {src, dinv[src]}
__global__ void scatter_kernel(const int* __restrict__ ei, const int* __restrict__ flag,
                               int* __restrict__ fill, const float* __restrict__ dinv,
                               int2* __restrict__ col2, int E) {
    int e = blockIdx.x * blockDim.x + threadIdx.x;
    if (e >= E) return;
    int is64 = *flag;
    int s = load_idx(ei, (long long)e, is64);
    int d = load_idx(ei, (long long)E + e, is64);
    int pos = atomicAdd(&fill[d], 1);
    col2[pos] = make_int2(s, __float_as_int(dinv[s]));
}

// ---------------- weight pre-conversion: f32 [k][n] -> hi/lo bf16 [n][k] ----------------
__global__ void convertW_kernel(const float* __restrict__ W, unsigned short* __restrict__ hi,
                                unsigned short* __restrict__ lo, int N, int Npad) {
    int idx = blockIdx.x * blockDim.x + threadIdx.x;   // over Npad*128
    if (idx >= Npad * 128) return;
    int nn = idx >> 7, k = idx & 127;
    float v = (nn < N) ? W[k * N + nn] : 0.f;
    unsigned short h = f2bf(v);
    hi[idx] = h;
    lo[idx] = f2bf(v - bf2f(h));
}

// ---------------- split-bf16 MFMA GEMM  C[M x 128] = A[M x 128] @ W[128 x 128] ----
// C = Ahi*Whi + Ahi*Wlo + Alo*Whi (lo*lo dropped, ~2^-17 rel err).
__launch_bounds__(256)
__global__ void gemm128_mfma_kernel(const float* __restrict__ A, const unsigned short* __restrict__ Wcvt,
                                    float* __restrict__ C, int M) {
    __shared__ unsigned short Ah[64 * 128];   // 16KB, swizzled row-major [row][k]
    __shared__ unsigned short Al[64 * 128];   // 16KB
    int t = threadIdx.x;
    int l = t & 63, w = t >> 6;
    int lr = l & 15, lh = l >> 4;

    // --- W fragments: wave w owns cols n0..n0+31; 16B vector loads ---
    const unsigned short* Whi = Wcvt;               // [128n][128k]
    const unsigned short* Wlo = Wcvt + 128 * 128;
    short8v bhi[2][4], blo[2][4];
    int n0 = w * 32;
    #pragma unroll
    for (int ni = 0; ni < 2; ++ni) {
        int n = n0 + ni * 16 + lr;
        #pragma unroll
        for (int ks = 0; ks < 4; ++ks) {
            bhi[ni][ks] = *(const short8v*)&Whi[n * 128 + ks * 32 + lh * 8];
            blo[ni][ks] = *(const short8v*)&Wlo[n * 128 + ks * 32 + lh * 8];
        }
    }

    // --- stage A tile (64 rows x 128 k), f32 -> hi/lo bf16, swizzled ---
    int row0 = blockIdx.x * 64;
    #pragma unroll
    for (int c = 0; c < 4; ++c) {
        int chunk = c * 256 + t;          // 0..1023
        int r  = chunk >> 4;              // 0..63
        int kc = chunk & 15;              // 16B chunk within row (8 bf16)
        int gr = row0 + r; if (gr >= M) gr = M - 1;
        float4 a0 = *(const float4*)&A[(size_t)gr * 128 + kc * 8];
        float4 a1 = *(const float4*)&A[(size_t)gr * 128 + kc * 8 + 4];
        float av[8] = {a0.x, a0.y, a0.z, a0.w, a1.x, a1.y, a1.z, a1.w};
        short8v hv, lv;
        #pragma unroll
        for (int j = 0; j < 8; ++j) {
            unsigned short hi = f2bf(av[j]);
            hv[j] = (short)hi;
            lv[j] = (short)f2bf(av[j] - bf2f(hi));
        }
        int off = (r << 8) + ((kc << 4) ^ ((r & 7) << 4));   // byte offset
        *(short8v*)((char*)Ah + off) = hv;
        *(short8v*)((char*)Al + off) = lv;
    }
    __syncthreads();

    // --- MFMA: wave computes 64 rows x 32 cols ---
    f32x4 acc[4][2];
    #pragma unroll
    for (int mi = 0; mi < 4; ++mi)
        #pragma unroll
        for (int ni = 0; ni < 2; ++ni)
            acc[mi][ni] = (f32x4){0.f, 0.f, 0.f, 0.f};

    #pragma unroll
    for (int mi = 0; mi < 4; ++mi) {
        int row = mi * 16 + lr;
        #pragma unroll
        for (int ks = 0; ks < 4; ++ks) {
            int off = (row << 8) + (((ks << 6) + (lh << 4)) ^ ((row & 7) << 4));
            short8v ah = *(short8v*)((char*)Ah + off);
            short8v al = *(short8v*)((char*)Al + off);
            #pragma unroll
            for (int ni = 0; ni < 2; ++ni) {
                acc[mi][ni] = __builtin_amdgcn_mfma_f32_16x16x32_bf16(ah, bhi[ni][ks], acc[mi][ni], 0, 0, 0);
                acc[mi][ni] = __builtin_amdgcn_mfma_f32_16x16x32_bf16(ah, blo[ni][ks], acc[mi][ni], 0, 0, 0);
                acc[mi][ni] = __builtin_amdgcn_mfma_f32_16x16x32_bf16(al, bhi[ni][ks], acc[mi][ni], 0, 0, 0);
            }
        }
    }

    // --- write C: D layout col=lane&15, row=(lane>>4)*4+reg ---
    #pragma unroll
    for (int mi = 0; mi < 4; ++mi) {
        #pragma unroll
        for (int ni = 0; ni < 2; ++ni) {
            #pragma unroll
            for (int r = 0; r < 4; ++r) {
                int row = row0 + mi * 16 + lh * 4 + r;
                if (row < M) C[(size_t)row * 128 + n0 + ni * 16 + lr] = acc[mi][ni][r];
            }
        }
    }
}

// ---------------- CSR aggregate + bias + relu ----------------
// 32 lanes x float4 per node; batches of 8 gathers with next-batch col2
// prefetch (breaks the col-load -> gather serial latency chain).
__launch_bounds__(256)
__global__ void aggregate_kernel(const float4* __restrict__ h4, const float* __restrict__ dinv,
                                 const int* __restrict__ rowptr, const int2* __restrict__ col2,
                                 const float* __restrict__ bias, float4* __restrict__ out4, int n) {
    int node = blockIdx.x * 8 + (threadIdx.x >> 5);
    if (node >= n) return;
    int l = threadIdx.x & 31;
    float dn = dinv[node];
    size_t rowbase = (size_t)node * 32;
    float4 hv = h4[rowbase + l];
    float4 acc;
    acc.x = hv.x * dn; acc.y = hv.y * dn; acc.z = hv.z * dn; acc.w = hv.w * dn;
    int e = rowptr[node], e1 = rowptr[node + 1];
    int2 c[8];
    #pragma unroll
    for (int j = 0; j < 8; ++j)
        c[j] = (e + j < e1) ? col2[e + j] : make_int2(node, 0);   // pad: zero-weight self
    while (e < e1) {
        int en = e + 8;
        int2 cn[8];
        #pragma unroll
        for (int j = 0; j < 8; ++j)
            cn[j] = (en + j < e1) ? col2[en + j] : make_int2(node, 0);
        float4 v[8];
        #pragma unroll
        for (int j = 0; j < 8; ++j) v[j] = h4[(size_t)c[j].x * 32 + l];
        #pragma unroll
        for (int j = 0; j < 8; ++j) {
            float ds = __int_as_float(c[j].y);
            acc.x += v[j].x * ds; acc.y += v[j].y * ds;
            acc.z += v[j].z * ds; acc.w += v[j].w * ds;
        }
        #pragma unroll
        for (int j = 0; j < 8; ++j) c[j] = cn[j];
        e = en;
    }
    float4 bv = *(const float4*)&bias[l * 4];
    float4 o;
    o.x = fmaxf(acc.x * dn + bv.x, 0.f);
    o.y = fmaxf(acc.y * dn + bv.y, 0.f);
    o.z = fmaxf(acc.z * dn + bv.z, 0.f);
    o.w = fmaxf(acc.w * dn + bv.w, 0.f);
    out4[rowbase + l] = o;
}

// ---------------- MFMA final layer  C[M x 40] = A[M x 128] @ Wf[128 x 40] + bf ------
// N padded to 48 (3 n-tiles), split-bf16 like gemm128.
__launch_bounds__(256)
__global__ void final_mfma_kernel(const float* __restrict__ A, const unsigned short* __restrict__ Wcvt,
                                  const float* __restrict__ bf, float* __restrict__ C, int M) {
    __shared__ unsigned short Ah[64 * 128];
    __shared__ unsigned short Al[64 * 128];
    int t = threadIdx.x;
    int l = t & 63, w = t >> 6;
    int lr = l & 15, lh = l >> 4;

    const unsigned short* Whi = Wcvt;            // [48n][128k]
    const unsigned short* Wlo = Wcvt + 48 * 128;
    short8v bhi[3][4], blo[3][4];
    #pragma unroll
    for (int nt = 0; nt < 3; ++nt) {
        int n = nt * 16 + lr;
        #pragma unroll
        for (int ks = 0; ks < 4; ++ks) {
            bhi[nt][ks] = *(const short8v*)&Whi[n * 128 + ks * 32 + lh * 8];
            blo[nt][ks] = *(const short8v*)&Wlo[n * 128 + ks * 32 + lh * 8];
        }
    }

    int row0 = blockIdx.x * 64;
    #pragma unroll
    for (int c = 0; c < 4; ++c) {
        int chunk = c * 256 + t;
        int r  = chunk >> 4;
        int kc = chunk & 15;
        int gr = row0 + r; if (gr >= M) gr = M - 1;
        float4 a0 = *(const float4*)&A[(size_t)gr * 128 + kc * 8];
        float4 a1 = *(const float4*)&A[(size_t)gr * 128 + kc * 8 + 4];
        float av[8] = {a0.x, a0.y, a0.z, a0.w, a1.x, a1.y, a1.z, a1.w};
        short8v hv, lv;
        #pragma unroll
        for (int j = 0; j < 8; ++j) {
            unsigned short hi = f2bf(av[j]);
            hv[j] = (short)hi;
            lv[j] = (short)f2bf(av[j] - bf2f(hi));
        }
        int off = (r << 8) + ((kc << 4) ^ ((r & 7) << 4));
        *(short8v*)((char*)Ah + off) = hv;
        *(short8v*)((char*)Al + off) = lv;
    }
    __syncthreads();

    // wave w computes rows w*16..w*16+15, all 3 n-tiles
    f32x4 acc[3];
    #pragma unroll
    for (int nt = 0; nt < 3; ++nt) acc[nt] = (f32x4){0.f, 0.f, 0.f, 0.f};
    int row = w * 16 + lr;
    #pragma unroll
    for (int ks = 0; ks < 4; ++ks) {
        int off = (row << 8) + (((ks << 6) + (lh << 4)) ^ ((row & 7) << 4));
        short8v ah = *(short8v*)((char*)Ah + off);
        short8v al = *(short8v*)((char*)Al + off);
        #pragma unroll
        for (int nt = 0; nt < 3; ++nt) {
            acc[nt] = __builtin_amdgcn_mfma_f32_16x16x32_bf16(ah, bhi[nt][ks], acc[nt], 0, 0, 0);
            acc[nt] = __builtin_amdgcn_mfma_f32_16x16x32_bf16(ah, blo[nt][ks], acc[nt], 0, 0, 0);
            acc[nt] = __builtin_amdgcn_mfma_f32_16x16x32_bf16(al, bhi[nt][ks], acc[nt], 0, 0, 0);
        }
    }
    #pragma unroll
    for (int nt = 0; nt < 3; ++nt) {
        int col = nt * 16 + lr;
        #pragma unroll
        for (int r = 0; r < 4; ++r) {
            int ro = row0 + w * 16 + lh * 4 + r;
            if (col < NC && ro < M) C[(size_t)ro * NC + col] = acc[nt][r] + bf[col];
        }
    }
}

extern "C" void kernel_launch(void* const* d_in, const int* in_sizes, int n_in,
                              void* d_out, int out_size, void* d_ws, size_t ws_size,
                              hipStream_t stream) {
    const float* x  = (const float*)d_in[0];
    const int*   ei = (const int*)d_in[1];
    const float* W1 = (const float*)d_in[2];
    const float* b1 = (const float*)d_in[3];
    const float* Wh = (const float*)d_in[4];
    const float* bh = (const float*)d_in[5];
    const float* Wf = (const float*)d_in[6];
    const float* bf = (const float*)d_in[7];
    float* out = (float*)d_out;

    int n = in_sizes[0] / D;    // 50000
    int E = in_sizes[1] / 2;    // 800000

    char* ws = (char*)d_ws;
    size_t off = 0;
    auto alloc = [&](size_t bytes) {
        void* p = ws + off;
        off = (off + bytes + 255) & ~(size_t)255;
        return p;
    };
    float* B0     = (float*)alloc((size_t)n * D * 4);
    float* B1     = (float*)alloc((size_t)n * D * 4);
    int*   deg    = (int*)alloc((size_t)n * 4);
    int*   rowptr = (int*)alloc((size_t)(n + 1) * 4);
    int*   fill   = (int*)alloc((size_t)n * 4);
    int2*  col2   = (int2*)alloc((size_t)E * 8);
    float* dinv   = (float*)alloc((size_t)n * 4);
    int*   flag   = (int*)alloc(256);
    int*   bsum   = (int*)alloc(1024 * 4);
    int*   total  = (int*)alloc(256);
    unsigned short* Wc1  = (unsigned short*)alloc(2 * 128 * 128 * 2);
    unsigned short* Wch0 = (unsigned short*)alloc(2 * 128 * 128 * 2);
    unsigned short* Wch1 = (unsigned short*)alloc(2 * 128 * 128 * 2);
    unsigned short* Wcf  = (unsigned short*)alloc(2 * 48 * 128 * 2);

    int nb = (n + 255) / 256;

    hipMemsetAsync(deg, 0, (size_t)n * 4, stream);
    detect_kernel<<<1, 256, 0, stream>>>(ei, flag);
    count_deg_kernel<<<(E + 255) / 256, 256, 0, stream>>>(ei, flag, deg, E);
    scan1_kernel<<<nb, 256, 0, stream>>>(deg, bsum, n);
    scan2_kernel<<<1, 1024, 0, stream>>>(bsum, total, nb);
    scan3_kernel<<<nb, 256, 0, stream>>>(deg, bsum, total, rowptr, fill, dinv, n);
    scatter_kernel<<<(E + 255) / 256, 256, 0, stream>>>(ei, flag, fill, dinv, col2, E);

    convertW_kernel<<<(128 * 128 + 255) / 256, 256, 0, stream>>>(W1, Wc1, Wc1 + 128 * 128, 128, 128);
    convertW_kernel<<<(128 * 128 + 255) / 256, 256, 0, stream>>>(Wh, Wch0, Wch0 + 128 * 128, 128, 128);
    convertW_kernel<<<(128 * 128 + 255) / 256, 256, 0, stream>>>(Wh + 128 * 128, Wch1, Wch1 + 128 * 128, 128, 128);
    convertW_kernel<<<(48 * 128 + 255) / 256, 256, 0, stream>>>(Wf, Wcf, Wcf + 48 * 128, 40, 48);

    int gblocks = (n + 63) / 64;
    int agrid = (n + 7) / 8;

    gemm128_mfma_kernel<<<gblocks, 256, 0, stream>>>(x, Wc1, B0, n);
    aggregate_kernel<<<agrid, 256, 0, stream>>>((const float4*)B0, dinv, rowptr, col2, b1, (float4*)B1, n);
    gemm128_mfma_kernel<<<gblocks, 256, 0, stream>>>(B1, Wch0, B0, n);
    aggregate_kernel<<<agrid, 256, 0, stream>>>((const float4*)B0, dinv, rowptr, col2, bh, (float4*)B1, n);
    gemm128_mfma_kernel<<<gblocks, 256, 0, stream>>>(B1, Wch1, B0, n);
    aggregate_kernel<<<agrid, 256, 0, stream>>>((const float4*)B0, dinv, rowptr, col2, bh + D, (float4*)B1, n);
    final_mfma_kernel<<<gblocks, 256, 0, stream>>>(B1, Wcf, bf, out, n);
}

// Round 5
// 347.013 us; speedup vs baseline: 2.0722x; 1.0240x over previous
//
#include <hip/hip_runtime.h>

#define D 128
#define NC 40
#define CH_SHIFT 13               // src-chunk = 8192 nodes = 4MB f32 rows (1 XCD L2)

typedef __attribute__((ext_vector_type(8))) short short8v;
typedef __attribute__((ext_vector_type(4))) float f32x4;

__device__ __forceinline__ unsigned short f2bf(float f) {
    unsigned u = __float_as_uint(f);
    u += 0x7fff + ((u >> 16) & 1);          // RNE
    return (unsigned short)(u >> 16);
}
__device__ __forceinline__ float bf2f(unsigned short h) {
    return __uint_as_float(((unsigned)h) << 16);
}

// ---------------- graph build ----------------

__global__ void detect_kernel(const int* __restrict__ ei, int* __restrict__ flag) {
    __shared__ int any;
    if (threadIdx.x == 0) any = 0;
    __syncthreads();
    if (ei[threadIdx.x * 2 + 1] != 0) any = 1;   // benign race
    __syncthreads();
    if (threadIdx.x == 0) *flag = (any == 0) ? 1 : 0;  // 1 == int64
}

__device__ __forceinline__ int load_idx(const int* ei, long long pos, int is64) {
    return is64 ? ei[pos * 2] : ei[pos];
}

// per-(dst, src-chunk) degree count
__global__ void count_deg2_kernel(const int* __restrict__ ei, const int* __restrict__ flag,
                                  int* __restrict__ deg2, int E, int NCH) {
    int e = blockIdx.x * blockDim.x + threadIdx.x;
    if (e >= E) return;
    int is64 = *flag;
    int s = load_idx(ei, (long long)e, is64);
    int d = load_idx(ei, (long long)E + e, is64);
    atomicAdd(&deg2[(size_t)d * NCH + (s >> CH_SHIFT)], 1);
}

// 3-phase parallel exclusive scan over m = n*NCH entries (512-thread blocks)
__global__ void scan1_kernel(const int* __restrict__ deg2, int* __restrict__ bsum, int m) {
    int i = blockIdx.x * 512 + threadIdx.x;
    int v = (i < m) ? deg2[i] : 0;
    #pragma unroll
    for (int off = 32; off; off >>= 1) v += __shfl_down(v, off, 64);
    __shared__ int ws[8];
    if ((threadIdx.x & 63) == 0) ws[threadIdx.x >> 6] = v;
    __syncthreads();
    if (threadIdx.x == 0) {
        int s = 0;
        #pragma unroll
        for (int j = 0; j < 8; ++j) s += ws[j];
        bsum[blockIdx.x] = s;
    }
}

__global__ void scan2_kernel(int* __restrict__ bsum, int* __restrict__ total, int nb) {
    int t = threadIdx.x;                 // 1024 threads, nb <= 1024
    int lane = t & 63, w = t >> 6;
    int v = (t < nb) ? bsum[t] : 0;
    int s = v;
    #pragma unroll
    for (int off = 1; off < 64; off <<= 1) {
        int x = __shfl_up(s, off, 64);
        if (lane >= off) s += x;
    }
    __shared__ int wsum[16];
    if (lane == 63) wsum[w] = s;
    __syncthreads();
    int wbase = 0;
    #pragma unroll
    for (int j = 0; j < 16; ++j) if (j < w) wbase += wsum[j];
    int excl = wbase + s - v;
    if (t < nb) bsum[t] = excl;
    if (t == nb - 1) *total = excl + v;
}

__global__ void scan3_kernel(const int* __restrict__ deg2, const int* __restrict__ bsum,
                             const int* __restrict__ total, int* __restrict__ rowptr2,
                             int* __restrict__ fill2, int m) {
    int i = blockIdx.x * 512 + threadIdx.x;
    int v = (i < m) ? deg2[i] : 0;
    int lane = threadIdx.x & 63, w = threadIdx.x >> 6;
    int s = v;
    #pragma unroll
    for (int off = 1; off < 64; off <<= 1) {
        int x = __shfl_up(s, off, 64);
        if (lane >= off) s += x;
    }
    __shared__ int wsum[8];
    if (lane == 63) wsum[w] = s;
    __syncthreads();
    int wbase = 0;
    #pragma unroll
    for (int j = 0; j < 8; ++j) if (j < w) wbase += wsum[j];
    int excl = bsum[blockIdx.x] + wbase + s - v;
    if (i < m) {
        rowptr2[i] = excl;
        fill2[i]   = excl;
    }
    if (i == 0) rowptr2[m] = *total;
}

// dinv from per-node rowptr2 span (degree = edge count; +1 for self loop)
__global__ void dinv_kernel(const int* __restrict__ rowptr2, float* __restrict__ dinv,
                            int n, int NCH) {
    int i = blockIdx.x * 256 + threadIdx.x;
    if (i >= n) return;
    int deg = rowptr2[(size_t)(i + 1) * NCH] - rowptr2[(size_t)i * NCH];
    dinv[i] = rsqrtf((float)(deg + 1));
}

// scatter edge -> chunked CSR, packing {src, dinv[src]}
__global__ void scatter_kernel(const int* __restrict__ ei, const int* __restrict__ flag,
                               int* __restrict__ fill2, const float* __restrict__ dinv,
                               int2* __restrict__ col2, int E, int NCH) {
    int e = blockIdx.x * blockDim.x + threadIdx.x;
    if (e >= E) return;
    int is64 = *flag;
    int s = load_idx(ei, (long long)e, is64);
    int d = load_idx(ei, (long long)E + e, is64);
    int pos = atomicAdd(&fill2[(size_t)d * NCH + (s >> CH_SHIFT)], 1);
    col2[pos] = make_int2(s, __float_as_int(dinv[s]));
}

// ---------------- weight pre-conversion: f32 [k][n] -> hi/lo bf16 [n][k] ----------------
__global__ void convertW_kernel(const float* __restrict__ W, unsigned short* __restrict__ hi,
                                unsigned short* __restrict__ lo, int N, int Npad) {
    int idx = blockIdx.x * blockDim.x + threadIdx.x;   // over Npad*128
    if (idx >= Npad * 128) return;
    int nn = idx >> 7, k = idx & 127;
    float v = (nn < N) ? W[k * N + nn] : 0.f;
    unsigned short h = f2bf(v);
    hi[idx] = h;
    lo[idx] = f2bf(v - bf2f(h));
}

// ---------------- split-bf16 MFMA GEMM  C[M x 128] = A[M x 128] @ W[128 x 128] ----
__launch_bounds__(256)
__global__ void gemm128_mfma_kernel(const float* __restrict__ A, const unsigned short* __restrict__ Wcvt,
                                    float* __restrict__ C, int M) {
    __shared__ unsigned short Ah[64 * 128];   // 16KB, swizzled row-major [row][k]
    __shared__ unsigned short Al[64 * 128];   // 16KB
    int t = threadIdx.x;
    int l = t & 63, w = t >> 6;
    int lr = l & 15, lh = l >> 4;

    const unsigned short* Whi = Wcvt;               // [128n][128k]
    const unsigned short* Wlo = Wcvt + 128 * 128;
    short8v bhi[2][4], blo[2][4];
    int n0 = w * 32;
    #pragma unroll
    for (int ni = 0; ni < 2; ++ni) {
        int n = n0 + ni * 16 + lr;
        #pragma unroll
        for (int ks = 0; ks < 4; ++ks) {
            bhi[ni][ks] = *(const short8v*)&Whi[n * 128 + ks * 32 + lh * 8];
            blo[ni][ks] = *(const short8v*)&Wlo[n * 128 + ks * 32 + lh * 8];
        }
    }

    int row0 = blockIdx.x * 64;
    #pragma unroll
    for (int c = 0; c < 4; ++c) {
        int chunk = c * 256 + t;          // 0..1023
        int r  = chunk >> 4;              // 0..63
        int kc = chunk & 15;              // 16B chunk within row (8 bf16)
        int gr = row0 + r; if (gr >= M) gr = M - 1;
        float4 a0 = *(const float4*)&A[(size_t)gr * 128 + kc * 8];
        float4 a1 = *(const float4*)&A[(size_t)gr * 128 + kc * 8 + 4];
        float av[8] = {a0.x, a0.y, a0.z, a0.w, a1.x, a1.y, a1.z, a1.w};
        short8v hv, lv;
        #pragma unroll
        for (int j = 0; j < 8; ++j) {
            unsigned short hi = f2bf(av[j]);
            hv[j] = (short)hi;
            lv[j] = (short)f2bf(av[j] - bf2f(hi));
        }
        int off = (r << 8) + ((kc << 4) ^ ((r & 7) << 4));   // byte offset
        *(short8v*)((char*)Ah + off) = hv;
        *(short8v*)((char*)Al + off) = lv;
    }
    __syncthreads();

    f32x4 acc[4][2];
    #pragma unroll
    for (int mi = 0; mi < 4; ++mi)
        #pragma unroll
        for (int ni = 0; ni < 2; ++ni)
            acc[mi][ni] = (f32x4){0.f, 0.f, 0.f, 0.f};

    #pragma unroll
    for (int mi = 0; mi < 4; ++mi) {
        int row = mi * 16 + lr;
        #pragma unroll
        for (int ks = 0; ks < 4; ++ks) {
            int off = (row << 8) + (((ks << 6) + (lh << 4)) ^ ((row & 7) << 4));
            short8v ah = *(short8v*)((char*)Ah + off);
            short8v al = *(short8v*)((char*)Al + off);
            #pragma unroll
            for (int ni = 0; ni < 2; ++ni) {
                acc[mi][ni] = __builtin_amdgcn_mfma_f32_16x16x32_bf16(ah, bhi[ni][ks], acc[mi][ni], 0, 0, 0);
                acc[mi][ni] = __builtin_amdgcn_mfma_f32_16x16x32_bf16(ah, blo[ni][ks], acc[mi][ni], 0, 0, 0);
                acc[mi][ni] = __builtin_amdgcn_mfma_f32_16x16x32_bf16(al, bhi[ni][ks], acc[mi][ni], 0, 0, 0);
            }
        }
    }

    #pragma unroll
    for (int mi = 0; mi < 4; ++mi) {
        #pragma unroll
        for (int ni = 0; ni < 2; ++ni) {
            #pragma unroll
            for (int r = 0; r < 4; ++r) {
                int row = row0 + mi * 16 + lh * 4 + r;
                if (row < M) C[(size_t)row * 128 + n0 + ni * 16 + lr] = acc[mi][ni][r];
            }
        }
    }
}

// ---------------- CSR aggregate + bias + relu (r2 body; chunked rowptr) -------
__launch_bounds__(256)
__global__ void aggregate_kernel(const float4* __restrict__ h4, const float* __restrict__ dinv,
                                 const int* __restrict__ rowptr2, const int2* __restrict__ col2,
                                 const float* __restrict__ bias, float4* __restrict__ out4,
                                 int n, int NCH) {
    int node = blockIdx.x * 8 + (threadIdx.x >> 5);
    if (node >= n) return;
    int l = threadIdx.x & 31;
    float dn = dinv[node];
    size_t rowbase = (size_t)node * 32;
    float4 hv = h4[rowbase + l];
    float4 acc;
    acc.x = hv.x * dn; acc.y = hv.y * dn; acc.z = hv.z * dn; acc.w = hv.w * dn;
    int e = rowptr2[(size_t)node * NCH], e1 = rowptr2[(size_t)(node + 1) * NCH];
    for (; e + 8 <= e1; e += 8) {
        int2 c[8];
        #pragma unroll
        for (int j = 0; j < 8; ++j) c[j] = col2[e + j];
        float4 v[8];
        #pragma unroll
        for (int j = 0; j < 8; ++j) v[j] = h4[(size_t)c[j].x * 32 + l];
        #pragma unroll
        for (int j = 0; j < 8; ++j) {
            float ds = __int_as_float(c[j].y);
            acc.x += v[j].x * ds; acc.y += v[j].y * ds;
            acc.z += v[j].z * ds; acc.w += v[j].w * ds;
        }
    }
    for (; e + 4 <= e1; e += 4) {
        int2 c[4];
        #pragma unroll
        for (int j = 0; j < 4; ++j) c[j] = col2[e + j];
        float4 v[4];
        #pragma unroll
        for (int j = 0; j < 4; ++j) v[j] = h4[(size_t)c[j].x * 32 + l];
        #pragma unroll
        for (int j = 0; j < 4; ++j) {
            float ds = __int_as_float(c[j].y);
            acc.x += v[j].x * ds; acc.y += v[j].y * ds;
            acc.z += v[j].z * ds; acc.w += v[j].w * ds;
        }
    }
    for (; e < e1; ++e) {
        int2 c = col2[e];
        float ds = __int_as_float(c.y);
        float4 v = h4[(size_t)c.x * 32 + l];
        acc.x += v.x * ds; acc.y += v.y * ds; acc.z += v.z * ds; acc.w += v.w * ds;
    }
    float4 bv = *(const float4*)&bias[l * 4];
    float4 o;
    o.x = fmaxf(acc.x * dn + bv.x, 0.f);
    o.y = fmaxf(acc.y * dn + bv.y, 0.f);
    o.z = fmaxf(acc.z * dn + bv.z, 0.f);
    o.w = fmaxf(acc.w * dn + bv.w, 0.f);
    out4[rowbase + l] = o;
}

// ---------------- MFMA final layer  C[M x 40] = A[M x 128] @ Wf[128 x 40] + bf ------
__launch_bounds__(256)
__global__ void final_mfma_kernel(const float* __restrict__ A, const unsigned short* __restrict__ Wcvt,
                                  const float* __restrict__ bf, float* __restrict__ C, int M) {
    __shared__ unsigned short Ah[64 * 128];
    __shared__ unsigned short Al[64 * 128];
    int t = threadIdx.x;
    int l = t & 63, w = t >> 6;
    int lr = l & 15, lh = l >> 4;

    const unsigned short* Whi = Wcvt;            // [48n][128k]
    const unsigned short* Wlo = Wcvt + 48 * 128;
    short8v bhi[3][4], blo[3][4];
    #pragma unroll
    for (int nt = 0; nt < 3; ++nt) {
        int n = nt * 16 + lr;
        #pragma unroll
        for (int ks = 0; ks < 4; ++ks) {
            bhi[nt][ks] = *(const short8v*)&Whi[n * 128 + ks * 32 + lh * 8];
            blo[nt][ks] = *(const short8v*)&Wlo[n * 128 + ks * 32 + lh * 8];
        }
    }

    int row0 = blockIdx.x * 64;
    #pragma unroll
    for (int c = 0; c < 4; ++c) {
        int chunk = c * 256 + t;
        int r  = chunk >> 4;
        int kc = chunk & 15;
        int gr = row0 + r; if (gr >= M) gr = M - 1;
        float4 a0 = *(const float4*)&A[(size_t)gr * 128 + kc * 8];
        float4 a1 = *(const float4*)&A[(size_t)gr * 128 + kc * 8 + 4];
        float av[8] = {a0.x, a0.y, a0.z, a0.w, a1.x, a1.y, a1.z, a1.w};
        short8v hv, lv;
        #pragma unroll
        for (int j = 0; j < 8; ++j) {
            unsigned short hi = f2bf(av[j]);
            hv[j] = (short)hi;
            lv[j] = (short)f2bf(av[j] - bf2f(hi));
        }
        int off = (r << 8) + ((kc << 4) ^ ((r & 7) << 4));
        *(short8v*)((char*)Ah + off) = hv;
        *(short8v*)((char*)Al + off) = lv;
    }
    __syncthreads();

    f32x4 acc[3];
    #pragma unroll
    for (int nt = 0; nt < 3; ++nt) acc[nt] = (f32x4){0.f, 0.f, 0.f, 0.f};
    int row = w * 16 + lr;
    #pragma unroll
    for (int ks = 0; ks < 4; ++ks) {
        int off = (row << 8) + (((ks << 6) + (lh << 4)) ^ ((row & 7) << 4));
        short8v ah = *(short8v*)((char*)Ah + off);
        short8v al = *(short8v*)((char*)Al + off);
        #pragma unroll
        for (int nt = 0; nt < 3; ++nt) {
            acc[nt] = __builtin_amdgcn_mfma_f32_16x16x32_bf16(ah, bhi[nt][ks], acc[nt], 0, 0, 0);
            acc[nt] = __builtin_amdgcn_mfma_f32_16x16x32_bf16(ah, blo[nt][ks], acc[nt], 0, 0, 0);
            acc[nt] = __builtin_amdgcn_mfma_f32_16x16x32_bf16(al, bhi[nt][ks], acc[nt], 0, 0, 0);
        }
    }
    #pragma unroll
    for (int nt = 0; nt < 3; ++nt) {
        int col = nt * 16 + lr;
        #pragma unroll
        for (int r = 0; r < 4; ++r) {
            int ro = row0 + w * 16 + lh * 4 + r;
            if (col < NC && ro < M) C[(size_t)ro * NC + col] = acc[nt][r] + bf[col];
        }
    }
}

extern "C" void kernel_launch(void* const* d_in, const int* in_sizes, int n_in,
                              void* d_out, int out_size, void* d_ws, size_t ws_size,
                              hipStream_t stream) {
    const float* x  = (const float*)d_in[0];
    const int*   ei = (const int*)d_in[1];
    const float* W1 = (const float*)d_in[2];
    const float* b1 = (const float*)d_in[3];
    const float* Wh = (const float*)d_in[4];
    const float* bh = (const float*)d_in[5];
    const float* Wf = (const float*)d_in[6];
    const float* bf = (const float*)d_in[7];
    float* out = (float*)d_out;

    int n = in_sizes[0] / D;    // 50000
    int E = in_sizes[1] / 2;    // 800000
    int NCH = (n + (1 << CH_SHIFT) - 1) >> CH_SHIFT;   // 7 for n=50000
    int m = n * NCH;

    char* ws = (char*)d_ws;
    size_t off = 0;
    auto alloc = [&](size_t bytes) {
        void* p = ws + off;
        off = (off + bytes + 255) & ~(size_t)255;
        return p;
    };
    float* B0     = (float*)alloc((size_t)n * D * 4);
    float* B1     = (float*)alloc((size_t)n * D * 4);
    int*   deg2   = (int*)alloc((size_t)m * 4);
    int*   rowptr2= (int*)alloc((size_t)(m + 1) * 4);
    int*   fill2  = (int*)alloc((size_t)m * 4);
    int2*  col2   = (int2*)alloc((size_t)E * 8);
    float* dinv   = (float*)alloc((size_t)n * 4);
    int*   flag   = (int*)alloc(256);
    int*   bsum   = (int*)alloc(1024 * 4);
    int*   total  = (int*)alloc(256);
    unsigned short* Wc1  = (unsigned short*)alloc(2 * 128 * 128 * 2);
    unsigned short* Wch0 = (unsigned short*)alloc(2 * 128 * 128 * 2);
    unsigned short* Wch1 = (unsigned short*)alloc(2 * 128 * 128 * 2);
    unsigned short* Wcf  = (unsigned short*)alloc(2 * 48 * 128 * 2);

    int nb = (m + 511) / 512;   // 684 for n=50000 (<=1024 required by scan2)

    hipMemsetAsync(deg2, 0, (size_t)m * 4, stream);
    detect_kernel<<<1, 256, 0, stream>>>(ei, flag);
    count_deg2_kernel<<<(E + 255) / 256, 256, 0, stream>>>(ei, flag, deg2, E, NCH);
    scan1_kernel<<<nb, 512, 0, stream>>>(deg2, bsum, m);
    scan2_kernel<<<1, 1024, 0, stream>>>(bsum, total, nb);
    scan3_kernel<<<nb, 512, 0, stream>>>(deg2, bsum, total, rowptr2, fill2, m);
    dinv_kernel<<<(n + 255) / 256, 256, 0, stream>>>(rowptr2, dinv, n, NCH);
    scatter_kernel<<<(E + 255) / 256, 256, 0, stream>>>(ei, flag, fill2, dinv, col2, E, NCH);

    convertW_kernel<<<(128 * 128 + 255) / 256, 256, 0, stream>>>(W1, Wc1, Wc1 + 128 * 128, 128, 128);
    convertW_kernel<<<(128 * 128 + 255) / 256, 256, 0, stream>>>(Wh, Wch0, Wch0 + 128 * 128, 128, 128);
    convertW_kernel<<<(128 * 128 + 255) / 256, 256, 0, stream>>>(Wh + 128 * 128, Wch1, Wch1 + 128 * 128, 128, 128);
    convertW_kernel<<<(48 * 128 + 255) / 256, 256, 0, stream>>>(Wf, Wcf, Wcf + 48 * 128, 40, 48);

    int gblocks = (n + 63) / 64;
    int agrid = (n + 7) / 8;

    gemm128_mfma_kernel<<<gblocks, 256, 0, stream>>>(x, Wc1, B0, n);
    aggregate_kernel<<<agrid, 256, 0, stream>>>((const float4*)B0, dinv, rowptr2, col2, b1, (float4*)B1, n, NCH);
    gemm128_mfma_kernel<<<gblocks, 256, 0, stream>>>(B1, Wch0, B0, n);
    aggregate_kernel<<<agrid, 256, 0, stream>>>((const float4*)B0, dinv, rowptr2, col2, bh, (float4*)B1, n, NCH);
    gemm128_mfma_kernel<<<gblocks, 256, 0, stream>>>(B1, Wch1, B0, n);
    aggregate_kernel<<<agrid, 256, 0, stream>>>((const float4*)B0, dinv, rowptr2, col2, bh + D, (float4*)B1, n, NCH);
    final_mfma_kernel<<<gblocks, 256, 0, stream>>>(B1, Wcf, bf, out, n);
}